// Round 14
// baseline (1384.201 us; speedup 1.0000x reference)
//
#include <hip/hip_runtime.h>
#include <hip/hip_bf16.h>

#define XROWS 8192
#define CROWS 32768
#define DIM   768
#define KSEL  32
#define CAND_CAP 256
#define TAU 0.095f
#define WIN_W 0.003f   // rescore half-width: ~6.5 sigma of i8 sim err (sigma ~ 4.6e-4)

typedef __attribute__((ext_vector_type(8))) short bf16x8;
typedef __attribute__((ext_vector_type(4))) short s16x4;
typedef __attribute__((ext_vector_type(4))) float f32x4;
typedef __attribute__((ext_vector_type(4))) int   i32x4;

__device__ inline short f2bf(float f) {
    unsigned int b = __builtin_bit_cast(unsigned int, f);
    b += 0x7fffu + ((b >> 16) & 1u);
    return (short)(b >> 16);
}
__device__ inline float bf2f(unsigned short u) {
    unsigned int b = ((unsigned int)u) << 16;
    return __builtin_bit_cast(float, b);
}

__device__ inline void gload_lds16(const void* g, void* l) {
    __builtin_amdgcn_global_load_lds((const __attribute__((address_space(1))) void*)g,
                                     (__attribute__((address_space(3))) void*)l,
                                     16, 0, 0);
}

// ============ pre-pass: norms + i8-quantized normalized copies + raw bf16 cb ====
__global__ __launch_bounds__(256) void convert_i8_kernel(const float* __restrict__ x,
                                                         const float* __restrict__ cb,
                                                         float* __restrict__ inv_all,
                                                         float* __restrict__ qsc,
                                                         char* __restrict__ xq,
                                                         char* __restrict__ cq,
                                                         short* __restrict__ cbr) {
    int wid  = (blockIdx.x * blockDim.x + threadIdx.x) >> 6;  // one wave per row
    int lane = threadIdx.x & 63;
    if (wid >= XROWS + CROWS) return;
    const float* src = (wid < XROWS) ? (x + (size_t)wid * DIM)
                                     : (cb + (size_t)(wid - XROWS) * DIM);
    char* dst = (wid < XROWS) ? (xq + (size_t)wid * DIM)
                              : (cq + (size_t)(wid - XROWS) * DIM);
    f32x4 v[3];
    float ss = 0.f, am = 0.f;
#pragma unroll
    for (int j = 0; j < 3; ++j) {
        v[j] = *(const f32x4*)&src[(lane + 64 * j) * 4];
        ss += v[j][0]*v[j][0] + v[j][1]*v[j][1] + v[j][2]*v[j][2] + v[j][3]*v[j][3];
        am = fmaxf(am, fmaxf(fmaxf(fabsf(v[j][0]), fabsf(v[j][1])),
                             fmaxf(fabsf(v[j][2]), fabsf(v[j][3]))));
    }
#pragma unroll
    for (int s = 32; s >= 1; s >>= 1) {
        ss += __shfl_xor(ss, s, 64);
        am = fmaxf(am, __shfl_xor(am, s, 64));
    }
    float inv  = 1.0f / fmaxf(sqrtf(ss), 1e-8f);
    float amn  = fmaxf(am * inv, 1e-8f);     // absmax of normalized row
    float qs   = amn * (1.0f / 127.0f);
    float iq   = 127.0f / amn;
    if (lane == 0) { inv_all[wid] = inv; qsc[wid] = qs; }
#pragma unroll
    for (int j = 0; j < 3; ++j) {
        int b0 = __float2int_rn(fminf(fmaxf(v[j][0] * inv * iq, -127.f), 127.f)) & 0xff;
        int b1 = __float2int_rn(fminf(fmaxf(v[j][1] * inv * iq, -127.f), 127.f)) & 0xff;
        int b2 = __float2int_rn(fminf(fmaxf(v[j][2] * inv * iq, -127.f), 127.f)) & 0xff;
        int b3 = __float2int_rn(fminf(fmaxf(v[j][3] * inv * iq, -127.f), 127.f)) & 0xff;
        *(int*)&dst[(size_t)(lane + 64 * j) * 4] = b0 | (b1 << 8) | (b2 << 16) | (b3 << 24);
    }
    if (cbr != nullptr && wid >= XROWS) {   // RAW bf16 copy (NOT normalized!)
        short* d2 = cbr + (size_t)(wid - XROWS) * DIM;
#pragma unroll
        for (int j = 0; j < 3; ++j) {
            s16x4 o;
            o[0] = f2bf(v[j][0]); o[1] = f2bf(v[j][1]);
            o[2] = f2bf(v[j][2]); o[3] = f2bf(v[j][3]);
            *(s16x4*)&d2[(lane + 64 * j) * 4] = o;
        }
    }
}

// ============ filter12: i8 128x128, NO LDS — frags loaded directly from L2 ======
// Same wave->output mapping as filter11 (8 waves x 32x64, 2x4 frags), but each
// frag is a per-lane global_load_dwordx4 (16 rows x one fully-consumed 64B line).
// A-band (8x98KB) + B-panels are L2-resident under this bid map (FETCH flat at
// ~102MB across R10-R13). No barriers, no vmcnt convoys; 12-tile full unroll
// lets the compiler pipeline loads; zero LDS -> occupancy capped only by VGPR.
#define NT8 12   // 768/64

__global__ __launch_bounds__(512, 8) void filter12_kernel(const char* __restrict__ xq,
                                                          const char* __restrict__ cq,
                                                          const float* __restrict__ qsc,
                                                          int* __restrict__ cnt,
                                                          int2* __restrict__ cand) {
    const int bid  = blockIdx.x;
    const int rt   = ((bid & 7) << 3) | ((bid >> 3) & 7);
    const int ct   = bid >> 6;
    const int row0 = rt * 128;
    const int col0 = ct * 128;

    const int t      = threadIdx.x;   // 0..511
    const int lane   = t & 63;
    const int w      = t >> 6;        // 0..7
    const int wr     = w >> 1;        // 0..3: rows wr*32..+31
    const int wc     = w & 1;         // 0..1: cols wc*64..+63
    const int lane15 = lane & 15;
    const int slot   = lane >> 4;     // 16B k-slot within the 64B k-tile row

    // per-lane base addresses (frag m/n and tile kt add compile-time offsets)
    const char* abase = xq + (size_t)(row0 + wr * 32 + lane15) * DIM + slot * 16;
    const char* bbase = cq + (size_t)(col0 + wc * 64 + lane15) * DIM + slot * 16;

    i32x4 acc[2][4];
    const i32x4 izero = {0, 0, 0, 0};
#pragma unroll
    for (int m = 0; m < 2; ++m)
#pragma unroll
        for (int n = 0; n < 4; ++n) acc[m][n] = izero;

#pragma unroll
    for (int kt = 0; kt < NT8; ++kt) {
        i32x4 a_[2], b_[4];
#pragma unroll
        for (int m = 0; m < 2; ++m)
            a_[m] = *(const i32x4*)(abase + (size_t)m * 16 * DIM + kt * 64);
#pragma unroll
        for (int n = 0; n < 4; ++n)
            b_[n] = *(const i32x4*)(bbase + (size_t)n * 16 * DIM + kt * 64);
#pragma unroll
        for (int m = 0; m < 2; ++m)
#pragma unroll
            for (int n = 0; n < 4; ++n)
                acc[m][n] = __builtin_amdgcn_mfma_i32_16x16x64_i8(a_[m], b_[n], acc[m][n], 0, 0, 0);
    }

    // epilogue: dequant (qsc[row]*qsc[XROWS+col]) + threshold push
    const int rbase = row0 + wr * 32 + slot * 4;
    const int cbase = col0 + wc * 64 + lane15;
    float qc4[4];
#pragma unroll
    for (int n = 0; n < 4; ++n) qc4[n] = qsc[XROWS + cbase + n * 16];
#pragma unroll
    for (int m = 0; m < 2; ++m)
#pragma unroll
        for (int q = 0; q < 4; ++q) {
            const int row = rbase + m * 16 + q;
            const float qx = qsc[row];
#pragma unroll
            for (int n = 0; n < 4; ++n) {
                float s = (float)acc[m][n][q] * qx * qc4[n];
                if (s >= TAU) {
                    int col = cbase + n * 16;
                    int pos = atomicAdd(&cnt[row], 1);
                    if (pos < CAND_CAP)
                        cand[(size_t)row * CAND_CAP + pos] = make_int2(__float_as_int(s), col);
                }
            }
        }
}

// ============ fallback filter (fp32 inputs, small-ws path) ======================
#define BM 128
#define BN 128
#define FBK 32
#define NSEG 16
#define SEGCOLS (CROWS / NSEG)
__global__ __launch_bounds__(256) void filter_fb_kernel(const float* __restrict__ x,
                                                        const float* __restrict__ cb,
                                                        const float* __restrict__ inv_all,
                                                        int* __restrict__ cnt,
                                                        int2* __restrict__ cand) {
    __shared__ short As[BM][FBK + 8];
    __shared__ short Bs[BN][FBK + 8];
    const int rt   = blockIdx.x >> 4;
    const int seg  = blockIdx.x & 15;
    const int row0 = rt * BM;
    const int segc0 = seg * SEGCOLS;
    const int t    = threadIdx.x;
    const int lane = t & 63;
    const int w    = t >> 6;
    const int wr   = w >> 1, wc = w & 1;

    for (int ch = 0; ch < SEGCOLS / BN; ++ch) {
        const int col0 = segc0 + ch * BN;
        f32x4 acc[4][4];
        const f32x4 zero = {0.f, 0.f, 0.f, 0.f};
#pragma unroll
        for (int m = 0; m < 4; ++m)
#pragma unroll
            for (int n = 0; n < 4; ++n) acc[m][n] = zero;

        for (int kk = 0; kk < DIM; kk += FBK) {
            __syncthreads();
#pragma unroll
            for (int p = 0; p < 4; ++p) {
                int f4 = t + 256 * p;
                int r  = f4 >> 3;
                int c  = (f4 & 7) * 4;
                f32x4 v  = *(const f32x4*)&x[(size_t)(row0 + r) * DIM + kk + c];
                float iv = inv_all[row0 + r];
                s16x4 o;
                o[0] = f2bf(v[0] * iv); o[1] = f2bf(v[1] * iv);
                o[2] = f2bf(v[2] * iv); o[3] = f2bf(v[3] * iv);
                *(s16x4*)&As[r][c] = o;
            }
#pragma unroll
            for (int p = 0; p < 4; ++p) {
                int f4 = t + 256 * p;
                int r  = f4 >> 3;
                int c  = (f4 & 7) * 4;
                f32x4 v  = *(const f32x4*)&cb[(size_t)(col0 + r) * DIM + kk + c];
                float iv = inv_all[XROWS + col0 + r];
                s16x4 o;
                o[0] = f2bf(v[0] * iv); o[1] = f2bf(v[1] * iv);
                o[2] = f2bf(v[2] * iv); o[3] = f2bf(v[3] * iv);
                *(s16x4*)&Bs[r][c] = o;
            }
            __syncthreads();

            bf16x8 af[4], bfr[4];
#pragma unroll
            for (int m = 0; m < 4; ++m)
                af[m] = *(const bf16x8*)&As[wr * 64 + m * 16 + (lane & 15)][(lane >> 4) * 8];
#pragma unroll
            for (int n = 0; n < 4; ++n)
                bfr[n] = *(const bf16x8*)&Bs[wc * 64 + n * 16 + (lane & 15)][(lane >> 4) * 8];
#pragma unroll
            for (int m = 0; m < 4; ++m)
#pragma unroll
                for (int n = 0; n < 4; ++n)
                    acc[m][n] = __builtin_amdgcn_mfma_f32_16x16x32_bf16(af[m], bfr[n], acc[m][n], 0, 0, 0);
        }

        const int rbase = row0 + wr * 64 + (lane >> 4) * 4;
        const int cbase = col0 + wc * 64 + (lane & 15);
#pragma unroll
        for (int m = 0; m < 4; ++m)
#pragma unroll
            for (int n = 0; n < 4; ++n)
#pragma unroll
                for (int q = 0; q < 4; ++q) {
                    float s = acc[m][n][q];
                    if (s >= TAU) {
                        int row = rbase + m * 16 + q;
                        int col = cbase + n * 16;
                        int pos = atomicAdd(&cnt[row], 1);
                        if (pos < CAND_CAP)
                            cand[(size_t)row * CAND_CAP + pos] = make_int2(__float_as_int(s), col);
                    }
                }
    }
}

__global__ __launch_bounds__(256) void norm_kernel(const float* __restrict__ x,
                                                   const float* __restrict__ cb,
                                                   float* __restrict__ inv_all) {
    int wid  = (blockIdx.x * blockDim.x + threadIdx.x) >> 6;
    int lane = threadIdx.x & 63;
    if (wid >= XROWS + CROWS) return;
    const float* src = (wid < XROWS) ? (x + (size_t)wid * DIM)
                                     : (cb + (size_t)(wid - XROWS) * DIM);
    float ss = 0.f;
#pragma unroll
    for (int j = 0; j < 3; ++j) {
        f32x4 v = *(const f32x4*)&src[(lane + 64 * j) * 4];
        ss += v[0]*v[0] + v[1]*v[1] + v[2]*v[2] + v[3]*v[3];
    }
#pragma unroll
    for (int s = 32; s >= 1; s >>= 1) ss += __shfl_xor(ss, s, 64);
    if (lane == 0) inv_all[wid] = 1.0f / fmaxf(sqrtf(ss), 1e-8f);
}

// ============ refine: sort by est sim, 128-slot window exact rescore ============
__global__ __launch_bounds__(256) void refine_kernel(const float* __restrict__ x,
                                                     const float* __restrict__ cb,
                                                     const short* __restrict__ cbr,
                                                     const float* __restrict__ inv_all,
                                                     const int* __restrict__ cnt,
                                                     const int2* __restrict__ cand,
                                                     float* __restrict__ out) {
    __shared__ float xs[DIM];
    __shared__ float sv[CAND_CAP];
    __shared__ int   si[CAND_CAP];
    __shared__ float wsv[128];
    __shared__ int   wsi[128];
    __shared__ int   cdef[4], cwin[4];

    const int row = blockIdx.x;
    const int t   = threadIdx.x;
#pragma unroll
    for (int j = 0; j < 3; ++j) xs[t + 256 * j] = x[(size_t)row * DIM + t + 256 * j];

    int ncand = cnt[row];
    if (ncand > CAND_CAP) ncand = CAND_CAP;
    int2 c = (t < ncand) ? cand[(size_t)row * CAND_CAP + t]
                         : make_int2((int)0xFF800000u /* -inf */, 0x7fffffff);
    sv[t] = __int_as_float(c.x);
    si[t] = c.y;
    __syncthreads();

    // bitonic sort 256: descending sim, ties -> ascending idx
    for (int k2 = 2; k2 <= 256; k2 <<= 1) {
        for (int j = k2 >> 1; j > 0; j >>= 1) {
            __syncthreads();
            int p = t ^ j;
            if (p > t) {
                float s1 = sv[t], s2 = sv[p];
                int   i1 = si[t], i2 = si[p];
                bool lt_tp = (s1 < s2) || (s1 == s2 && i1 > i2);
                bool lt_pt = (s2 < s1) || (s1 == s2 && i2 > i1);
                bool doswap = ((t & k2) == 0) ? lt_tp : lt_pt;
                if (doswap) { sv[t] = s2; sv[p] = s1; si[t] = i2; si[p] = i1; }
            }
        }
    }
    __syncthreads();

    // classify: definite members (sv > B+W) / ambiguous window [B-W, B+W]
    const float B   = sv[31];
    const float WHI = B + WIN_W, WLO = B - WIN_W;
    bool defin = (sv[t] > WHI);
    bool win   = (sv[t] >= WLO) && !defin;
    unsigned long long bd = __ballot(defin);
    unsigned long long bw = __ballot(win);
    if ((t & 63) == 0) { cdef[t >> 6] = __popcll(bd); cwin[t >> 6] = __popcll(bw); }
    if (t < 128) { wsv[t] = -INFINITY; wsi[t] = 0x7fffffff; }
    __syncthreads();
    const int d = cdef[0] + cdef[1] + cdef[2] + cdef[3];   // <= 32
    int m = cwin[0] + cwin[1] + cwin[2] + cwin[3];
    if (m > 128) m = 128;

    // exact fp32 rescore of window positions d..d+m-1 (4 lanes per candidate)
    const int q = t >> 2, sub = t & 3;
#pragma unroll
    for (int p2 = 0; p2 < 2; ++p2) {
        int ci = p2 * 64 + q;
        if (ci < m) {
            int col = si[d + ci];
            if (col >= 0 && col < CROWS) {
                const float* cp = cb + (size_t)col * DIM;
                float a0 = 0.f, a1 = 0.f, a2 = 0.f, a3 = 0.f;
#pragma unroll 4
                for (int i = 0; i < 48; ++i) {
                    f32x4 c4 = *(const f32x4*)&cp[sub * 4 + i * 16];
                    f32x4 x4 = *(const f32x4*)&xs[sub * 4 + i * 16];
                    a0 = fmaf(x4[0], c4[0], a0);
                    a1 = fmaf(x4[1], c4[1], a1);
                    a2 = fmaf(x4[2], c4[2], a2);
                    a3 = fmaf(x4[3], c4[3], a3);
                }
                float dd = (a0 + a1) + (a2 + a3);
                dd += __shfl_xor(dd, 1, 64);
                dd += __shfl_xor(dd, 2, 64);
                if (sub == 0) {
                    wsv[ci] = dd * inv_all[row] * inv_all[XROWS + col];
                    wsi[ci] = col;
                }
            }
        }
    }
    __syncthreads();

    // bitonic sort 128 window entries: desc sim, ties -> asc idx
    for (int k2 = 2; k2 <= 128; k2 <<= 1) {
        for (int j = k2 >> 1; j > 0; j >>= 1) {
            if (t < 128) {
                int p = t ^ j;
                if (p > t) {
                    float s1 = wsv[t], s2 = wsv[p];
                    int   i1 = wsi[t], i2 = wsi[p];
                    bool lt_tp = (s1 < s2) || (s1 == s2 && i1 > i2);
                    bool lt_pt = (s2 < s1) || (s1 == s2 && i2 > i1);
                    bool doswap = ((t & k2) == 0) ? lt_tp : lt_pt;
                    if (doswap) { wsv[t] = s2; wsv[p] = s1; wsi[t] = i2; wsi[p] = i1; }
                }
            }
            __syncthreads();
        }
    }

    // final set: d definite + best (32-d) of window by exact sim
    float o0 = 0.f, o1 = 0.f, o2 = 0.f;
    if (cbr != nullptr) {
        for (int j = 0; j < KSEL; ++j) {
            int cc = (j < d) ? si[j] : wsi[j - d];
            if (cc >= 0 && cc < CROWS) {
                const unsigned short* rp = (const unsigned short*)(cbr + (size_t)cc * DIM);
                o0 += bf2f(rp[t]);
                o1 += bf2f(rp[t + 256]);
                o2 += bf2f(rp[t + 512]);
            }
        }
    } else {
        for (int j = 0; j < KSEL; ++j) {
            int cc = (j < d) ? si[j] : wsi[j - d];
            if (cc >= 0 && cc < CROWS) {
                o0 += cb[(size_t)cc * DIM + t];
                o1 += cb[(size_t)cc * DIM + t + 256];
                o2 += cb[(size_t)cc * DIM + t + 512];
            }
        }
    }
    out[(size_t)row * DIM + t]       = o0;
    out[(size_t)row * DIM + t + 256] = o1;
    out[(size_t)row * DIM + t + 512] = o2;
}

extern "C" void kernel_launch(void* const* d_in, const int* in_sizes, int n_in,
                              void* d_out, int out_size, void* d_ws, size_t ws_size,
                              hipStream_t stream) {
    const float* x  = (const float*)d_in[0];
    const float* cb = (const float*)d_in[1];
    float* out = (float*)d_out;

    // ws layout: cnt | cand(int2) | inv_all | qsc | xq i8 | cq i8 [| cbr bf16]
    char* base = (char*)d_ws;
    int*   cnt     = (int*)base;
    int2*  cand    = (int2*)(base + (size_t)XROWS * sizeof(int));
    size_t off_inv = (size_t)XROWS * sizeof(int) + (size_t)XROWS * CAND_CAP * sizeof(int2);
    float* inv_all = (float*)(base + off_inv);
    size_t off_qsc = off_inv + (size_t)(XROWS + CROWS) * sizeof(float);
    float* qsc     = (float*)(base + off_qsc);
    size_t off_xq  = (off_qsc + (size_t)(XROWS + CROWS) * sizeof(float) + 255) & ~(size_t)255;
    char*  xq      = base + off_xq;
    size_t off_cq  = off_xq + (size_t)XROWS * DIM;
    char*  cq      = base + off_cq;
    size_t need    = off_cq + (size_t)CROWS * DIM;
    size_t off_cbr = (need + 255) & ~(size_t)255;
    short* cbr     = (short*)(base + off_cbr);
    size_t need2   = off_cbr + (size_t)CROWS * DIM * sizeof(short);

    hipMemsetAsync(cnt, 0, XROWS * sizeof(int), stream);

    if (ws_size >= need) {
        short* cbr_arg = (ws_size >= need2) ? cbr : nullptr;
        convert_i8_kernel<<<(XROWS + CROWS) / 4, 256, 0, stream>>>(x, cb, inv_all, qsc, xq, cq, cbr_arg);
        filter12_kernel<<<(XROWS / 128) * (CROWS / 128), 512, 0, stream>>>(xq, cq, qsc, cnt, cand);
        refine_kernel<<<XROWS, 256, 0, stream>>>(x, cb, cbr_arg, inv_all, cnt, cand, out);
    } else {
        norm_kernel<<<(XROWS + CROWS) / 4, 256, 0, stream>>>(x, cb, inv_all);
        filter_fb_kernel<<<64 * NSEG, 256, 0, stream>>>(x, cb, inv_all, cnt, cand);
        refine_kernel<<<XROWS, 256, 0, stream>>>(x, cb, (const short*)nullptr, inv_all, cnt, cand, out);
    }
}

// Round 15
// 542.265 us; speedup vs baseline: 2.5526x; 2.5526x over previous
//
#include <hip/hip_runtime.h>
#include <hip/hip_bf16.h>

#define XROWS 8192
#define CROWS 32768
#define DIM   768
#define KSEL  32
#define CAND_CAP 256
#define TAU 0.095f
#define WIN_W 0.003f   // rescore half-width: ~6.5 sigma of i8 sim err (sigma ~ 4.6e-4)

typedef __attribute__((ext_vector_type(8))) short bf16x8;
typedef __attribute__((ext_vector_type(4))) short s16x4;
typedef __attribute__((ext_vector_type(4))) float f32x4;
typedef __attribute__((ext_vector_type(4))) int   i32x4;

__device__ inline short f2bf(float f) {
    unsigned int b = __builtin_bit_cast(unsigned int, f);
    b += 0x7fffu + ((b >> 16) & 1u);
    return (short)(b >> 16);
}
__device__ inline float bf2f(unsigned short u) {
    unsigned int b = ((unsigned int)u) << 16;
    return __builtin_bit_cast(float, b);
}

__device__ inline void gload_lds16(const void* g, void* l) {
    __builtin_amdgcn_global_load_lds((const __attribute__((address_space(1))) void*)g,
                                     (__attribute__((address_space(3))) void*)l,
                                     16, 0, 0);
}

// ============ pre-pass: norms + i8-quantized normalized copies + raw bf16 cb ====
__global__ __launch_bounds__(256) void convert_i8_kernel(const float* __restrict__ x,
                                                         const float* __restrict__ cb,
                                                         float* __restrict__ inv_all,
                                                         float* __restrict__ qsc,
                                                         char* __restrict__ xq,
                                                         char* __restrict__ cq,
                                                         short* __restrict__ cbr) {
    int wid  = (blockIdx.x * blockDim.x + threadIdx.x) >> 6;  // one wave per row
    int lane = threadIdx.x & 63;
    if (wid >= XROWS + CROWS) return;
    const float* src = (wid < XROWS) ? (x + (size_t)wid * DIM)
                                     : (cb + (size_t)(wid - XROWS) * DIM);
    char* dst = (wid < XROWS) ? (xq + (size_t)wid * DIM)
                              : (cq + (size_t)(wid - XROWS) * DIM);
    f32x4 v[3];
    float ss = 0.f, am = 0.f;
#pragma unroll
    for (int j = 0; j < 3; ++j) {
        v[j] = *(const f32x4*)&src[(lane + 64 * j) * 4];
        ss += v[j][0]*v[j][0] + v[j][1]*v[j][1] + v[j][2]*v[j][2] + v[j][3]*v[j][3];
        am = fmaxf(am, fmaxf(fmaxf(fabsf(v[j][0]), fabsf(v[j][1])),
                             fmaxf(fabsf(v[j][2]), fabsf(v[j][3]))));
    }
#pragma unroll
    for (int s = 32; s >= 1; s >>= 1) {
        ss += __shfl_xor(ss, s, 64);
        am = fmaxf(am, __shfl_xor(am, s, 64));
    }
    float inv  = 1.0f / fmaxf(sqrtf(ss), 1e-8f);
    float amn  = fmaxf(am * inv, 1e-8f);     // absmax of normalized row
    float qs   = amn * (1.0f / 127.0f);
    float iq   = 127.0f / amn;
    if (lane == 0) { inv_all[wid] = inv; qsc[wid] = qs; }
#pragma unroll
    for (int j = 0; j < 3; ++j) {
        int b0 = __float2int_rn(fminf(fmaxf(v[j][0] * inv * iq, -127.f), 127.f)) & 0xff;
        int b1 = __float2int_rn(fminf(fmaxf(v[j][1] * inv * iq, -127.f), 127.f)) & 0xff;
        int b2 = __float2int_rn(fminf(fmaxf(v[j][2] * inv * iq, -127.f), 127.f)) & 0xff;
        int b3 = __float2int_rn(fminf(fmaxf(v[j][3] * inv * iq, -127.f), 127.f)) & 0xff;
        *(int*)&dst[(size_t)(lane + 64 * j) * 4] = b0 | (b1 << 8) | (b2 << 16) | (b3 << 24);
    }
    if (cbr != nullptr && wid >= XROWS) {   // RAW bf16 copy (NOT normalized!)
        short* d2 = cbr + (size_t)(wid - XROWS) * DIM;
#pragma unroll
        for (int j = 0; j < 3; ++j) {
            s16x4 o;
            o[0] = f2bf(v[j][0]); o[1] = f2bf(v[j][1]);
            o[2] = f2bf(v[j][2]); o[3] = f2bf(v[j][3]);
            *(s16x4*)&d2[(lane + 64 * j) * 4] = o;
        }
    }
}

// ============ filter11 (R13-proven, 377us): i8 128x128 dbuf, 8w x (32x64) =======
// 32KB LDS / 4 blocks/CU, 512 threads -> 32 waves/CU (HW occupancy cap).
#define NT8 12   // 768/64

__device__ __forceinline__ i32x4 rdfrag_i8(const char* base, int row, int logslot) {
    int byte = (row << 6) + ((logslot ^ ((row >> 1) & 3)) << 4);
    return *(const i32x4*)(base + byte);
}

__global__ __launch_bounds__(512, 8) void filter11_kernel(const char* __restrict__ xq,
                                                          const char* __restrict__ cq,
                                                          const float* __restrict__ qsc,
                                                          int* __restrict__ cnt,
                                                          int2* __restrict__ cand) {
    __shared__ char As[2][128 * 64];   // 2 x 8 KB
    __shared__ char Bs[2][128 * 64];   // 2 x 8 KB  (32 KB total)

    const int bid  = blockIdx.x;
    const int rt   = ((bid & 7) << 3) | ((bid >> 3) & 7);
    const int ct   = bid >> 6;
    const int row0 = rt * 128;
    const int col0 = ct * 128;

    const int t      = threadIdx.x;   // 0..511
    const int lane   = t & 63;
    const int w      = t >> 6;        // 0..7
    const int wr     = w >> 1;        // 0..3: rows wr*32..+31
    const int wc     = w & 1;         // 0..1: cols wc*64..+63
    const int lane15 = lane & 15;
    const int slot   = lane >> 4;     // logical 16B k-slot, 0..3

    // staging: thread t covers tile byte f = t*16 (one A + one B load per tile)
    const int f_   = t * 16;
    const int sr_  = f_ >> 6;                               // row 0..127
    const int p_   = (f_ >> 4) & 3;                         // physical 16B chunk
    const int sce_ = (p_ ^ ((sr_ >> 1) & 3)) << 4;          // pre-swizzled src byte

#define STG(BUF_, KT_) do {                                                            \
    gload_lds16(&xq[(size_t)(row0 + sr_) * DIM + (KT_) * 64 + sce_],                   \
                (char*)&As[BUF_][0] + w * 1024);                                       \
    gload_lds16(&cq[(size_t)(col0 + sr_) * DIM + (KT_) * 64 + sce_],                   \
                (char*)&Bs[BUF_][0] + w * 1024);                                       \
} while (0)

    i32x4 acc[2][4];
    const i32x4 izero = {0, 0, 0, 0};
#pragma unroll
    for (int m = 0; m < 2; ++m)
#pragma unroll
        for (int n = 0; n < 4; ++n) acc[m][n] = izero;

    STG(0, 0);
    asm volatile("s_waitcnt vmcnt(0)" ::: "memory");
    __builtin_amdgcn_s_barrier();
    __builtin_amdgcn_sched_barrier(0);

#pragma unroll 1
    for (int kt = 0; kt < NT8; ++kt) {
        const int buf = kt & 1;
        if (kt + 1 < NT8) STG(buf ^ 1, kt + 1);   // other buf: sealed last barrier
        i32x4 a_[2], b_[4];
#pragma unroll
        for (int m = 0; m < 2; ++m)
            a_[m] = rdfrag_i8(&As[buf][0], wr * 32 + m * 16 + lane15, slot);
#pragma unroll
        for (int n = 0; n < 4; ++n)
            b_[n] = rdfrag_i8(&Bs[buf][0], wc * 64 + n * 16 + lane15, slot);
        asm volatile("s_waitcnt lgkmcnt(0)" ::: "memory");
        __builtin_amdgcn_sched_barrier(0);
        __builtin_amdgcn_s_setprio(1);
#pragma unroll
        for (int m = 0; m < 2; ++m)
#pragma unroll
            for (int n = 0; n < 4; ++n)
                acc[m][n] = __builtin_amdgcn_mfma_i32_16x16x64_i8(a_[m], b_[n], acc[m][n], 0, 0, 0);
        __builtin_amdgcn_s_setprio(0);
        asm volatile("s_waitcnt vmcnt(0)" ::: "memory");  // own 2 next-tile stages in
        __builtin_amdgcn_s_barrier();                     // all waves' stages landed
        __builtin_amdgcn_sched_barrier(0);
    }
#undef STG

    // epilogue: dequant (qsc[row]*qsc[XROWS+col]) + threshold push
    const int rbase = row0 + wr * 32 + slot * 4;
    const int cbase = col0 + wc * 64 + lane15;
    float qc4[4];
#pragma unroll
    for (int n = 0; n < 4; ++n) qc4[n] = qsc[XROWS + cbase + n * 16];
#pragma unroll
    for (int m = 0; m < 2; ++m)
#pragma unroll
        for (int q = 0; q < 4; ++q) {
            const int row = rbase + m * 16 + q;
            const float qx = qsc[row];
#pragma unroll
            for (int n = 0; n < 4; ++n) {
                float s = (float)acc[m][n][q] * qx * qc4[n];
                if (s >= TAU) {
                    int col = cbase + n * 16;
                    int pos = atomicAdd(&cnt[row], 1);
                    if (pos < CAND_CAP)
                        cand[(size_t)row * CAND_CAP + pos] = make_int2(__float_as_int(s), col);
                }
            }
        }
}

// ============ fallback filter (fp32 inputs, small-ws path) ======================
#define BM 128
#define BN 128
#define FBK 32
#define NSEG 16
#define SEGCOLS (CROWS / NSEG)
__global__ __launch_bounds__(256) void filter_fb_kernel(const float* __restrict__ x,
                                                        const float* __restrict__ cb,
                                                        const float* __restrict__ inv_all,
                                                        int* __restrict__ cnt,
                                                        int2* __restrict__ cand) {
    __shared__ short As[BM][FBK + 8];
    __shared__ short Bs[BN][FBK + 8];
    const int rt   = blockIdx.x >> 4;
    const int seg  = blockIdx.x & 15;
    const int row0 = rt * BM;
    const int segc0 = seg * SEGCOLS;
    const int t    = threadIdx.x;
    const int lane = t & 63;
    const int w    = t >> 6;
    const int wr   = w >> 1, wc = w & 1;

    for (int ch = 0; ch < SEGCOLS / BN; ++ch) {
        const int col0 = segc0 + ch * BN;
        f32x4 acc[4][4];
        const f32x4 zero = {0.f, 0.f, 0.f, 0.f};
#pragma unroll
        for (int m = 0; m < 4; ++m)
#pragma unroll
            for (int n = 0; n < 4; ++n) acc[m][n] = zero;

        for (int kk = 0; kk < DIM; kk += FBK) {
            __syncthreads();
#pragma unroll
            for (int p = 0; p < 4; ++p) {
                int f4 = t + 256 * p;
                int r  = f4 >> 3;
                int c  = (f4 & 7) * 4;
                f32x4 v  = *(const f32x4*)&x[(size_t)(row0 + r) * DIM + kk + c];
                float iv = inv_all[row0 + r];
                s16x4 o;
                o[0] = f2bf(v[0] * iv); o[1] = f2bf(v[1] * iv);
                o[2] = f2bf(v[2] * iv); o[3] = f2bf(v[3] * iv);
                *(s16x4*)&As[r][c] = o;
            }
#pragma unroll
            for (int p = 0; p < 4; ++p) {
                int f4 = t + 256 * p;
                int r  = f4 >> 3;
                int c  = (f4 & 7) * 4;
                f32x4 v  = *(const f32x4*)&cb[(size_t)(col0 + r) * DIM + kk + c];
                float iv = inv_all[XROWS + col0 + r];
                s16x4 o;
                o[0] = f2bf(v[0] * iv); o[1] = f2bf(v[1] * iv);
                o[2] = f2bf(v[2] * iv); o[3] = f2bf(v[3] * iv);
                *(s16x4*)&Bs[r][c] = o;
            }
            __syncthreads();

            bf16x8 af[4], bfr[4];
#pragma unroll
            for (int m = 0; m < 4; ++m)
                af[m] = *(const bf16x8*)&As[wr * 64 + m * 16 + (lane & 15)][(lane >> 4) * 8];
#pragma unroll
            for (int n = 0; n < 4; ++n)
                bfr[n] = *(const bf16x8*)&Bs[wc * 64 + n * 16 + (lane & 15)][(lane >> 4) * 8];
#pragma unroll
            for (int m = 0; m < 4; ++m)
#pragma unroll
                for (int n = 0; n < 4; ++n)
                    acc[m][n] = __builtin_amdgcn_mfma_f32_16x16x32_bf16(af[m], bfr[n], acc[m][n], 0, 0, 0);
        }

        const int rbase = row0 + wr * 64 + (lane >> 4) * 4;
        const int cbase = col0 + wc * 64 + (lane & 15);
#pragma unroll
        for (int m = 0; m < 4; ++m)
#pragma unroll
            for (int n = 0; n < 4; ++n)
#pragma unroll
                for (int q = 0; q < 4; ++q) {
                    float s = acc[m][n][q];
                    if (s >= TAU) {
                        int row = rbase + m * 16 + q;
                        int col = cbase + n * 16;
                        int pos = atomicAdd(&cnt[row], 1);
                        if (pos < CAND_CAP)
                            cand[(size_t)row * CAND_CAP + pos] = make_int2(__float_as_int(s), col);
                    }
                }
    }
}

__global__ __launch_bounds__(256) void norm_kernel(const float* __restrict__ x,
                                                   const float* __restrict__ cb,
                                                   float* __restrict__ inv_all) {
    int wid  = (blockIdx.x * blockDim.x + threadIdx.x) >> 6;
    int lane = threadIdx.x & 63;
    if (wid >= XROWS + CROWS) return;
    const float* src = (wid < XROWS) ? (x + (size_t)wid * DIM)
                                     : (cb + (size_t)(wid - XROWS) * DIM);
    float ss = 0.f;
#pragma unroll
    for (int j = 0; j < 3; ++j) {
        f32x4 v = *(const f32x4*)&src[(lane + 64 * j) * 4];
        ss += v[0]*v[0] + v[1]*v[1] + v[2]*v[2] + v[3]*v[3];
    }
#pragma unroll
    for (int s = 32; s >= 1; s >>= 1) ss += __shfl_xor(ss, s, 64);
    if (lane == 0) inv_all[wid] = 1.0f / fmaxf(sqrtf(ss), 1e-8f);
}

// ============ refine: sort by est sim, 128-slot window exact rescore ============
__global__ __launch_bounds__(256) void refine_kernel(const float* __restrict__ x,
                                                     const float* __restrict__ cb,
                                                     const short* __restrict__ cbr,
                                                     const float* __restrict__ inv_all,
                                                     const int* __restrict__ cnt,
                                                     const int2* __restrict__ cand,
                                                     float* __restrict__ out) {
    __shared__ float xs[DIM];
    __shared__ float sv[CAND_CAP];
    __shared__ int   si[CAND_CAP];
    __shared__ float wsv[128];
    __shared__ int   wsi[128];
    __shared__ int   cdef[4], cwin[4];

    const int row = blockIdx.x;
    const int t   = threadIdx.x;
#pragma unroll
    for (int j = 0; j < 3; ++j) xs[t + 256 * j] = x[(size_t)row * DIM + t + 256 * j];

    int ncand = cnt[row];
    if (ncand > CAND_CAP) ncand = CAND_CAP;
    int2 c = (t < ncand) ? cand[(size_t)row * CAND_CAP + t]
                         : make_int2((int)0xFF800000u /* -inf */, 0x7fffffff);
    sv[t] = __int_as_float(c.x);
    si[t] = c.y;
    __syncthreads();

    // bitonic sort 256: descending sim, ties -> ascending idx
    for (int k2 = 2; k2 <= 256; k2 <<= 1) {
        for (int j = k2 >> 1; j > 0; j >>= 1) {
            __syncthreads();
            int p = t ^ j;
            if (p > t) {
                float s1 = sv[t], s2 = sv[p];
                int   i1 = si[t], i2 = si[p];
                bool lt_tp = (s1 < s2) || (s1 == s2 && i1 > i2);
                bool lt_pt = (s2 < s1) || (s1 == s2 && i2 > i1);
                bool doswap = ((t & k2) == 0) ? lt_tp : lt_pt;
                if (doswap) { sv[t] = s2; sv[p] = s1; si[t] = i2; si[p] = i1; }
            }
        }
    }
    __syncthreads();

    // classify: definite members (sv > B+W) / ambiguous window [B-W, B+W]
    const float B   = sv[31];
    const float WHI = B + WIN_W, WLO = B - WIN_W;
    bool defin = (sv[t] > WHI);
    bool win   = (sv[t] >= WLO) && !defin;
    unsigned long long bd = __ballot(defin);
    unsigned long long bw = __ballot(win);
    if ((t & 63) == 0) { cdef[t >> 6] = __popcll(bd); cwin[t >> 6] = __popcll(bw); }
    if (t < 128) { wsv[t] = -INFINITY; wsi[t] = 0x7fffffff; }
    __syncthreads();
    const int d = cdef[0] + cdef[1] + cdef[2] + cdef[3];   // <= 32
    int m = cwin[0] + cwin[1] + cwin[2] + cwin[3];
    if (m > 128) m = 128;

    // exact fp32 rescore of window positions d..d+m-1 (4 lanes per candidate)
    const int q = t >> 2, sub = t & 3;
#pragma unroll
    for (int p2 = 0; p2 < 2; ++p2) {
        int ci = p2 * 64 + q;
        if (ci < m) {
            int col = si[d + ci];
            if (col >= 0 && col < CROWS) {
                const float* cp = cb + (size_t)col * DIM;
                float a0 = 0.f, a1 = 0.f, a2 = 0.f, a3 = 0.f;
#pragma unroll 4
                for (int i = 0; i < 48; ++i) {
                    f32x4 c4 = *(const f32x4*)&cp[sub * 4 + i * 16];
                    f32x4 x4 = *(const f32x4*)&xs[sub * 4 + i * 16];
                    a0 = fmaf(x4[0], c4[0], a0);
                    a1 = fmaf(x4[1], c4[1], a1);
                    a2 = fmaf(x4[2], c4[2], a2);
                    a3 = fmaf(x4[3], c4[3], a3);
                }
                float dd = (a0 + a1) + (a2 + a3);
                dd += __shfl_xor(dd, 1, 64);
                dd += __shfl_xor(dd, 2, 64);
                if (sub == 0) {
                    wsv[ci] = dd * inv_all[row] * inv_all[XROWS + col];
                    wsi[ci] = col;
                }
            }
        }
    }
    __syncthreads();

    // bitonic sort 128 window entries: desc sim, ties -> asc idx
    for (int k2 = 2; k2 <= 128; k2 <<= 1) {
        for (int j = k2 >> 1; j > 0; j >>= 1) {
            if (t < 128) {
                int p = t ^ j;
                if (p > t) {
                    float s1 = wsv[t], s2 = wsv[p];
                    int   i1 = wsi[t], i2 = wsi[p];
                    bool lt_tp = (s1 < s2) || (s1 == s2 && i1 > i2);
                    bool lt_pt = (s2 < s1) || (s1 == s2 && i2 > i1);
                    bool doswap = ((t & k2) == 0) ? lt_tp : lt_pt;
                    if (doswap) { wsv[t] = s2; wsv[p] = s1; wsi[t] = i2; wsi[p] = i1; }
                }
            }
            __syncthreads();
        }
    }

    // final set: d definite + best (32-d) of window by exact sim
    float o0 = 0.f, o1 = 0.f, o2 = 0.f;
    if (cbr != nullptr) {
        for (int j = 0; j < KSEL; ++j) {
            int cc = (j < d) ? si[j] : wsi[j - d];
            if (cc >= 0 && cc < CROWS) {
                const unsigned short* rp = (const unsigned short*)(cbr + (size_t)cc * DIM);
                o0 += bf2f(rp[t]);
                o1 += bf2f(rp[t + 256]);
                o2 += bf2f(rp[t + 512]);
            }
        }
    } else {
        for (int j = 0; j < KSEL; ++j) {
            int cc = (j < d) ? si[j] : wsi[j - d];
            if (cc >= 0 && cc < CROWS) {
                o0 += cb[(size_t)cc * DIM + t];
                o1 += cb[(size_t)cc * DIM + t + 256];
                o2 += cb[(size_t)cc * DIM + t + 512];
            }
        }
    }
    out[(size_t)row * DIM + t]       = o0;
    out[(size_t)row * DIM + t + 256] = o1;
    out[(size_t)row * DIM + t + 512] = o2;
}

extern "C" void kernel_launch(void* const* d_in, const int* in_sizes, int n_in,
                              void* d_out, int out_size, void* d_ws, size_t ws_size,
                              hipStream_t stream) {
    const float* x  = (const float*)d_in[0];
    const float* cb = (const float*)d_in[1];
    float* out = (float*)d_out;

    // ws layout: cnt | cand(int2) | inv_all | qsc | xq i8 | cq i8 [| cbr bf16]
    char* base = (char*)d_ws;
    int*   cnt     = (int*)base;
    int2*  cand    = (int2*)(base + (size_t)XROWS * sizeof(int));
    size_t off_inv = (size_t)XROWS * sizeof(int) + (size_t)XROWS * CAND_CAP * sizeof(int2);
    float* inv_all = (float*)(base + off_inv);
    size_t off_qsc = off_inv + (size_t)(XROWS + CROWS) * sizeof(float);
    float* qsc     = (float*)(base + off_qsc);
    size_t off_xq  = (off_qsc + (size_t)(XROWS + CROWS) * sizeof(float) + 255) & ~(size_t)255;
    char*  xq      = base + off_xq;
    size_t off_cq  = off_xq + (size_t)XROWS * DIM;
    char*  cq      = base + off_cq;
    size_t need    = off_cq + (size_t)CROWS * DIM;
    size_t off_cbr = (need + 255) & ~(size_t)255;
    short* cbr     = (short*)(base + off_cbr);
    size_t need2   = off_cbr + (size_t)CROWS * DIM * sizeof(short);

    hipMemsetAsync(cnt, 0, XROWS * sizeof(int), stream);

    if (ws_size >= need) {
        short* cbr_arg = (ws_size >= need2) ? cbr : nullptr;
        convert_i8_kernel<<<(XROWS + CROWS) / 4, 256, 0, stream>>>(x, cb, inv_all, qsc, xq, cq, cbr_arg);
        filter11_kernel<<<(XROWS / 128) * (CROWS / 128), 512, 0, stream>>>(xq, cq, qsc, cnt, cand);
        refine_kernel<<<XROWS, 256, 0, stream>>>(x, cb, cbr_arg, inv_all, cnt, cand, out);
    } else {
        norm_kernel<<<(XROWS + CROWS) / 4, 256, 0, stream>>>(x, cb, inv_all);
        filter_fb_kernel<<<64 * NSEG, 256, 0, stream>>>(x, cb, inv_all, cnt, cand);
        refine_kernel<<<XROWS, 256, 0, stream>>>(x, cb, (const short*)nullptr, inv_all, cnt, cand, out);
    }
}

// Round 16
// 540.587 us; speedup vs baseline: 2.5606x; 1.0031x over previous
//
#include <hip/hip_runtime.h>
#include <hip/hip_bf16.h>

#define XROWS 8192
#define CROWS 32768
#define DIM   768
#define KSEL  32
#define CAND_CAP 256
#define TAU 0.095f
#define WIN_W 0.003f   // rescore half-width: ~6.5 sigma of i8 sim err (sigma ~ 4.6e-4)

typedef __attribute__((ext_vector_type(8))) short bf16x8;
typedef __attribute__((ext_vector_type(4))) short s16x4;
typedef __attribute__((ext_vector_type(4))) float f32x4;
typedef __attribute__((ext_vector_type(4))) int   i32x4;
typedef __attribute__((ext_vector_type(4))) unsigned short u16x4;

__device__ inline short f2bf(float f) {
    unsigned int b = __builtin_bit_cast(unsigned int, f);
    b += 0x7fffu + ((b >> 16) & 1u);
    return (short)(b >> 16);
}
__device__ inline float bf2f(unsigned short u) {
    unsigned int b = ((unsigned int)u) << 16;
    return __builtin_bit_cast(float, b);
}

__device__ inline void gload_lds16(const void* g, void* l) {
    __builtin_amdgcn_global_load_lds((const __attribute__((address_space(1))) void*)g,
                                     (__attribute__((address_space(3))) void*)l,
                                     16, 0, 0);
}

// ============ pre-pass: norms + i8-quantized normalized copies + raw bf16 cb ====
__global__ __launch_bounds__(256) void convert_i8_kernel(const float* __restrict__ x,
                                                         const float* __restrict__ cb,
                                                         float* __restrict__ inv_all,
                                                         float* __restrict__ qsc,
                                                         char* __restrict__ xq,
                                                         char* __restrict__ cq,
                                                         short* __restrict__ cbr) {
    int wid  = (blockIdx.x * blockDim.x + threadIdx.x) >> 6;  // one wave per row
    int lane = threadIdx.x & 63;
    if (wid >= XROWS + CROWS) return;
    const float* src = (wid < XROWS) ? (x + (size_t)wid * DIM)
                                     : (cb + (size_t)(wid - XROWS) * DIM);
    char* dst = (wid < XROWS) ? (xq + (size_t)wid * DIM)
                              : (cq + (size_t)(wid - XROWS) * DIM);
    f32x4 v[3];
    float ss = 0.f, am = 0.f;
#pragma unroll
    for (int j = 0; j < 3; ++j) {
        v[j] = *(const f32x4*)&src[(lane + 64 * j) * 4];
        ss += v[j][0]*v[j][0] + v[j][1]*v[j][1] + v[j][2]*v[j][2] + v[j][3]*v[j][3];
        am = fmaxf(am, fmaxf(fmaxf(fabsf(v[j][0]), fabsf(v[j][1])),
                             fmaxf(fabsf(v[j][2]), fabsf(v[j][3]))));
    }
#pragma unroll
    for (int s = 32; s >= 1; s >>= 1) {
        ss += __shfl_xor(ss, s, 64);
        am = fmaxf(am, __shfl_xor(am, s, 64));
    }
    float inv  = 1.0f / fmaxf(sqrtf(ss), 1e-8f);
    float amn  = fmaxf(am * inv, 1e-8f);     // absmax of normalized row
    float qs   = amn * (1.0f / 127.0f);
    float iq   = 127.0f / amn;
    if (lane == 0) { inv_all[wid] = inv; qsc[wid] = qs; }
#pragma unroll
    for (int j = 0; j < 3; ++j) {
        int b0 = __float2int_rn(fminf(fmaxf(v[j][0] * inv * iq, -127.f), 127.f)) & 0xff;
        int b1 = __float2int_rn(fminf(fmaxf(v[j][1] * inv * iq, -127.f), 127.f)) & 0xff;
        int b2 = __float2int_rn(fminf(fmaxf(v[j][2] * inv * iq, -127.f), 127.f)) & 0xff;
        int b3 = __float2int_rn(fminf(fmaxf(v[j][3] * inv * iq, -127.f), 127.f)) & 0xff;
        *(int*)&dst[(size_t)(lane + 64 * j) * 4] = b0 | (b1 << 8) | (b2 << 16) | (b3 << 24);
    }
    if (cbr != nullptr && wid >= XROWS) {   // RAW bf16 copy (NOT normalized!)
        short* d2 = cbr + (size_t)(wid - XROWS) * DIM;
#pragma unroll
        for (int j = 0; j < 3; ++j) {
            s16x4 o;
            o[0] = f2bf(v[j][0]); o[1] = f2bf(v[j][1]);
            o[2] = f2bf(v[j][2]); o[3] = f2bf(v[j][3]);
            *(s16x4*)&d2[(lane + 64 * j) * 4] = o;
        }
    }
}

// ============ filter11 (R13-proven, 377us): i8 128x128 dbuf, 8w x (32x64) =======
// 32KB LDS / 4 blocks/CU, 512 threads -> 32 waves/CU (HW occupancy cap).
#define NT8 12   // 768/64

__device__ __forceinline__ i32x4 rdfrag_i8(const char* base, int row, int logslot) {
    int byte = (row << 6) + ((logslot ^ ((row >> 1) & 3)) << 4);
    return *(const i32x4*)(base + byte);
}

__global__ __launch_bounds__(512, 8) void filter11_kernel(const char* __restrict__ xq,
                                                          const char* __restrict__ cq,
                                                          const float* __restrict__ qsc,
                                                          int* __restrict__ cnt,
                                                          int2* __restrict__ cand) {
    __shared__ char As[2][128 * 64];   // 2 x 8 KB
    __shared__ char Bs[2][128 * 64];   // 2 x 8 KB  (32 KB total)

    const int bid  = blockIdx.x;
    const int rt   = ((bid & 7) << 3) | ((bid >> 3) & 7);
    const int ct   = bid >> 6;
    const int row0 = rt * 128;
    const int col0 = ct * 128;

    const int t      = threadIdx.x;   // 0..511
    const int lane   = t & 63;
    const int w      = t >> 6;        // 0..7
    const int wr     = w >> 1;        // 0..3: rows wr*32..+31
    const int wc     = w & 1;         // 0..1: cols wc*64..+63
    const int lane15 = lane & 15;
    const int slot   = lane >> 4;     // logical 16B k-slot, 0..3

    // staging: thread t covers tile byte f = t*16 (one A + one B load per tile)
    const int f_   = t * 16;
    const int sr_  = f_ >> 6;                               // row 0..127
    const int p_   = (f_ >> 4) & 3;                         // physical 16B chunk
    const int sce_ = (p_ ^ ((sr_ >> 1) & 3)) << 4;          // pre-swizzled src byte

#define STG(BUF_, KT_) do {                                                            \
    gload_lds16(&xq[(size_t)(row0 + sr_) * DIM + (KT_) * 64 + sce_],                   \
                (char*)&As[BUF_][0] + w * 1024);                                       \
    gload_lds16(&cq[(size_t)(col0 + sr_) * DIM + (KT_) * 64 + sce_],                   \
                (char*)&Bs[BUF_][0] + w * 1024);                                       \
} while (0)

    i32x4 acc[2][4];
    const i32x4 izero = {0, 0, 0, 0};
#pragma unroll
    for (int m = 0; m < 2; ++m)
#pragma unroll
        for (int n = 0; n < 4; ++n) acc[m][n] = izero;

    STG(0, 0);
    asm volatile("s_waitcnt vmcnt(0)" ::: "memory");
    __builtin_amdgcn_s_barrier();
    __builtin_amdgcn_sched_barrier(0);

#pragma unroll 1
    for (int kt = 0; kt < NT8; ++kt) {
        const int buf = kt & 1;
        if (kt + 1 < NT8) STG(buf ^ 1, kt + 1);   // other buf: sealed last barrier
        i32x4 a_[2], b_[4];
#pragma unroll
        for (int m = 0; m < 2; ++m)
            a_[m] = rdfrag_i8(&As[buf][0], wr * 32 + m * 16 + lane15, slot);
#pragma unroll
        for (int n = 0; n < 4; ++n)
            b_[n] = rdfrag_i8(&Bs[buf][0], wc * 64 + n * 16 + lane15, slot);
        asm volatile("s_waitcnt lgkmcnt(0)" ::: "memory");
        __builtin_amdgcn_sched_barrier(0);
        __builtin_amdgcn_s_setprio(1);
#pragma unroll
        for (int m = 0; m < 2; ++m)
#pragma unroll
            for (int n = 0; n < 4; ++n)
                acc[m][n] = __builtin_amdgcn_mfma_i32_16x16x64_i8(a_[m], b_[n], acc[m][n], 0, 0, 0);
        __builtin_amdgcn_s_setprio(0);
        asm volatile("s_waitcnt vmcnt(0)" ::: "memory");  // own 2 next-tile stages in
        __builtin_amdgcn_s_barrier();                     // all waves' stages landed
        __builtin_amdgcn_sched_barrier(0);
    }
#undef STG

    // epilogue: dequant (qsc[row]*qsc[XROWS+col]) + threshold push
    const int rbase = row0 + wr * 32 + slot * 4;
    const int cbase = col0 + wc * 64 + lane15;
    float qc4[4];
#pragma unroll
    for (int n = 0; n < 4; ++n) qc4[n] = qsc[XROWS + cbase + n * 16];
#pragma unroll
    for (int m = 0; m < 2; ++m)
#pragma unroll
        for (int q = 0; q < 4; ++q) {
            const int row = rbase + m * 16 + q;
            const float qx = qsc[row];
#pragma unroll
            for (int n = 0; n < 4; ++n) {
                float s = (float)acc[m][n][q] * qx * qc4[n];
                if (s >= TAU) {
                    int col = cbase + n * 16;
                    int pos = atomicAdd(&cnt[row], 1);
                    if (pos < CAND_CAP)
                        cand[(size_t)row * CAND_CAP + pos] = make_int2(__float_as_int(s), col);
                }
            }
        }
}

// ============ fallback filter (fp32 inputs, small-ws path) ======================
#define BM 128
#define BN 128
#define FBK 32
#define NSEG 16
#define SEGCOLS (CROWS / NSEG)
__global__ __launch_bounds__(256) void filter_fb_kernel(const float* __restrict__ x,
                                                        const float* __restrict__ cb,
                                                        const float* __restrict__ inv_all,
                                                        int* __restrict__ cnt,
                                                        int2* __restrict__ cand) {
    __shared__ short As[BM][FBK + 8];
    __shared__ short Bs[BN][FBK + 8];
    const int rt   = blockIdx.x >> 4;
    const int seg  = blockIdx.x & 15;
    const int row0 = rt * BM;
    const int segc0 = seg * SEGCOLS;
    const int t    = threadIdx.x;
    const int lane = t & 63;
    const int w    = t >> 6;
    const int wr   = w >> 1, wc = w & 1;

    for (int ch = 0; ch < SEGCOLS / BN; ++ch) {
        const int col0 = segc0 + ch * BN;
        f32x4 acc[4][4];
        const f32x4 zero = {0.f, 0.f, 0.f, 0.f};
#pragma unroll
        for (int m = 0; m < 4; ++m)
#pragma unroll
            for (int n = 0; n < 4; ++n) acc[m][n] = zero;

        for (int kk = 0; kk < DIM; kk += FBK) {
            __syncthreads();
#pragma unroll
            for (int p = 0; p < 4; ++p) {
                int f4 = t + 256 * p;
                int r  = f4 >> 3;
                int c  = (f4 & 7) * 4;
                f32x4 v  = *(const f32x4*)&x[(size_t)(row0 + r) * DIM + kk + c];
                float iv = inv_all[row0 + r];
                s16x4 o;
                o[0] = f2bf(v[0] * iv); o[1] = f2bf(v[1] * iv);
                o[2] = f2bf(v[2] * iv); o[3] = f2bf(v[3] * iv);
                *(s16x4*)&As[r][c] = o;
            }
#pragma unroll
            for (int p = 0; p < 4; ++p) {
                int f4 = t + 256 * p;
                int r  = f4 >> 3;
                int c  = (f4 & 7) * 4;
                f32x4 v  = *(const f32x4*)&cb[(size_t)(col0 + r) * DIM + kk + c];
                float iv = inv_all[XROWS + col0 + r];
                s16x4 o;
                o[0] = f2bf(v[0] * iv); o[1] = f2bf(v[1] * iv);
                o[2] = f2bf(v[2] * iv); o[3] = f2bf(v[3] * iv);
                *(s16x4*)&Bs[r][c] = o;
            }
            __syncthreads();

            bf16x8 af[4], bfr[4];
#pragma unroll
            for (int m = 0; m < 4; ++m)
                af[m] = *(const bf16x8*)&As[wr * 64 + m * 16 + (lane & 15)][(lane >> 4) * 8];
#pragma unroll
            for (int n = 0; n < 4; ++n)
                bfr[n] = *(const bf16x8*)&Bs[wc * 64 + n * 16 + (lane & 15)][(lane >> 4) * 8];
#pragma unroll
            for (int m = 0; m < 4; ++m)
#pragma unroll
                for (int n = 0; n < 4; ++n)
                    acc[m][n] = __builtin_amdgcn_mfma_f32_16x16x32_bf16(af[m], bfr[n], acc[m][n], 0, 0, 0);
        }

        const int rbase = row0 + wr * 64 + (lane >> 4) * 4;
        const int cbase = col0 + wc * 64 + (lane & 15);
#pragma unroll
        for (int m = 0; m < 4; ++m)
#pragma unroll
            for (int n = 0; n < 4; ++n)
#pragma unroll
                for (int q = 0; q < 4; ++q) {
                    float s = acc[m][n][q];
                    if (s >= TAU) {
                        int row = rbase + m * 16 + q;
                        int col = cbase + n * 16;
                        int pos = atomicAdd(&cnt[row], 1);
                        if (pos < CAND_CAP)
                            cand[(size_t)row * CAND_CAP + pos] = make_int2(__float_as_int(s), col);
                    }
                }
    }
}

__global__ __launch_bounds__(256) void norm_kernel(const float* __restrict__ x,
                                                   const float* __restrict__ cb,
                                                   float* __restrict__ inv_all) {
    int wid  = (blockIdx.x * blockDim.x + threadIdx.x) >> 6;
    int lane = threadIdx.x & 63;
    if (wid >= XROWS + CROWS) return;
    const float* src = (wid < XROWS) ? (x + (size_t)wid * DIM)
                                     : (cb + (size_t)(wid - XROWS) * DIM);
    float ss = 0.f;
#pragma unroll
    for (int j = 0; j < 3; ++j) {
        f32x4 v = *(const f32x4*)&src[(lane + 64 * j) * 4];
        ss += v[0]*v[0] + v[1]*v[1] + v[2]*v[2] + v[3]*v[3];
    }
#pragma unroll
    for (int s = 32; s >= 1; s >>= 1) ss += __shfl_xor(ss, s, 64);
    if (lane == 0) inv_all[wid] = 1.0f / fmaxf(sqrtf(ss), 1e-8f);
}

// ============ refine V4: octet rescore (8 lanes/cand) + vectorized gather =======
__global__ __launch_bounds__(256) void refine_kernel(const float* __restrict__ x,
                                                     const float* __restrict__ cb,
                                                     const short* __restrict__ cbr,
                                                     const float* __restrict__ inv_all,
                                                     const int* __restrict__ cnt,
                                                     const int2* __restrict__ cand,
                                                     float* __restrict__ out) {
    __shared__ float xs[DIM];
    __shared__ float sv[CAND_CAP];
    __shared__ int   si[CAND_CAP];
    __shared__ float wsv[128];
    __shared__ int   wsi[128];
    __shared__ int   cdef[4], cwin[4];

    const int row = blockIdx.x;
    const int t   = threadIdx.x;
#pragma unroll
    for (int j = 0; j < 3; ++j) xs[t + 256 * j] = x[(size_t)row * DIM + t + 256 * j];

    int ncand = cnt[row];
    if (ncand > CAND_CAP) ncand = CAND_CAP;
    int2 c = (t < ncand) ? cand[(size_t)row * CAND_CAP + t]
                         : make_int2((int)0xFF800000u /* -inf */, 0x7fffffff);
    sv[t] = __int_as_float(c.x);
    si[t] = c.y;
    __syncthreads();

    // bitonic sort 256: descending sim, ties -> ascending idx
    for (int k2 = 2; k2 <= 256; k2 <<= 1) {
        for (int j = k2 >> 1; j > 0; j >>= 1) {
            __syncthreads();
            int p = t ^ j;
            if (p > t) {
                float s1 = sv[t], s2 = sv[p];
                int   i1 = si[t], i2 = si[p];
                bool lt_tp = (s1 < s2) || (s1 == s2 && i1 > i2);
                bool lt_pt = (s2 < s1) || (s1 == s2 && i2 > i1);
                bool doswap = ((t & k2) == 0) ? lt_tp : lt_pt;
                if (doswap) { sv[t] = s2; sv[p] = s1; si[t] = i2; si[p] = i1; }
            }
        }
    }
    __syncthreads();

    // classify: definite members (sv > B+W) / ambiguous window [B-W, B+W]
    const float B   = sv[31];
    const float WHI = B + WIN_W, WLO = B - WIN_W;
    bool defin = (sv[t] > WHI);
    bool win   = (sv[t] >= WLO) && !defin;
    unsigned long long bd = __ballot(defin);
    unsigned long long bw = __ballot(win);
    if ((t & 63) == 0) { cdef[t >> 6] = __popcll(bd); cwin[t >> 6] = __popcll(bw); }
    if (t < 128) { wsv[t] = -INFINITY; wsi[t] = 0x7fffffff; }
    __syncthreads();
    const int d = cdef[0] + cdef[1] + cdef[2] + cdef[3];   // <= 32
    int m = cwin[0] + cwin[1] + cwin[2] + cwin[3];
    if (m > 128) m = 128;

    // exact fp32 rescore, 8 lanes per candidate (octets: lanes 8i..8i+7)
    const int oct = t >> 3, sub8 = t & 7;
#pragma unroll
    for (int p2 = 0; p2 < 4; ++p2) {
        int ci = p2 * 32 + oct;
        if (ci < m) {
            int col = si[d + ci];
            if (col >= 0 && col < CROWS) {
                const float* cp = cb + (size_t)col * DIM;
                float a0 = 0.f, a1 = 0.f, a2 = 0.f, a3 = 0.f;
#pragma unroll 4
                for (int i = 0; i < 24; ++i) {
                    f32x4 c4 = *(const f32x4*)&cp[sub8 * 4 + i * 32];
                    f32x4 x4 = *(const f32x4*)&xs[sub8 * 4 + i * 32];
                    a0 = fmaf(x4[0], c4[0], a0);
                    a1 = fmaf(x4[1], c4[1], a1);
                    a2 = fmaf(x4[2], c4[2], a2);
                    a3 = fmaf(x4[3], c4[3], a3);
                }
                float dd = (a0 + a1) + (a2 + a3);
                dd += __shfl_xor(dd, 1, 64);
                dd += __shfl_xor(dd, 2, 64);
                dd += __shfl_xor(dd, 4, 64);
                if (sub8 == 0) {
                    wsv[ci] = dd * inv_all[row] * inv_all[XROWS + col];
                    wsi[ci] = col;
                }
            }
        }
    }
    __syncthreads();

    // bitonic sort 128 window entries: desc sim, ties -> asc idx
    for (int k2 = 2; k2 <= 128; k2 <<= 1) {
        for (int j = k2 >> 1; j > 0; j >>= 1) {
            if (t < 128) {
                int p = t ^ j;
                if (p > t) {
                    float s1 = wsv[t], s2 = wsv[p];
                    int   i1 = wsi[t], i2 = wsi[p];
                    bool lt_tp = (s1 < s2) || (s1 == s2 && i1 > i2);
                    bool lt_pt = (s2 < s1) || (s1 == s2 && i2 > i1);
                    bool doswap = ((t & k2) == 0) ? lt_tp : lt_pt;
                    if (doswap) { wsv[t] = s2; wsv[p] = s1; wsi[t] = i2; wsi[p] = i1; }
                }
            }
            __syncthreads();
        }
    }

    // final set: d definite + best (32-d) of window; vectorized gather-sum.
    // thread t<192 owns 4 consecutive elements (t*4 .. t*4+3).
    if (t < 192) {
        float o0 = 0.f, o1 = 0.f, o2 = 0.f, o3 = 0.f;
        if (cbr != nullptr) {
            for (int j = 0; j < KSEL; ++j) {
                int cc = (j < d) ? si[j] : wsi[j - d];
                if (cc >= 0 && cc < CROWS) {
                    u16x4 r4 = *(const u16x4*)((const unsigned short*)(cbr + (size_t)cc * DIM) + t * 4);
                    o0 += bf2f(r4[0]);
                    o1 += bf2f(r4[1]);
                    o2 += bf2f(r4[2]);
                    o3 += bf2f(r4[3]);
                }
            }
        } else {
            for (int j = 0; j < KSEL; ++j) {
                int cc = (j < d) ? si[j] : wsi[j - d];
                if (cc >= 0 && cc < CROWS) {
                    f32x4 r4 = *(const f32x4*)&cb[(size_t)cc * DIM + t * 4];
                    o0 += r4[0];
                    o1 += r4[1];
                    o2 += r4[2];
                    o3 += r4[3];
                }
            }
        }
        f32x4 ov = {o0, o1, o2, o3};
        *(f32x4*)&out[(size_t)row * DIM + t * 4] = ov;
    }
}

extern "C" void kernel_launch(void* const* d_in, const int* in_sizes, int n_in,
                              void* d_out, int out_size, void* d_ws, size_t ws_size,
                              hipStream_t stream) {
    const float* x  = (const float*)d_in[0];
    const float* cb = (const float*)d_in[1];
    float* out = (float*)d_out;

    // ws layout: cnt | cand(int2) | inv_all | qsc | xq i8 | cq i8 [| cbr bf16]
    char* base = (char*)d_ws;
    int*   cnt     = (int*)base;
    int2*  cand    = (int2*)(base + (size_t)XROWS * sizeof(int));
    size_t off_inv = (size_t)XROWS * sizeof(int) + (size_t)XROWS * CAND_CAP * sizeof(int2);
    float* inv_all = (float*)(base + off_inv);
    size_t off_qsc = off_inv + (size_t)(XROWS + CROWS) * sizeof(float);
    float* qsc     = (float*)(base + off_qsc);
    size_t off_xq  = (off_qsc + (size_t)(XROWS + CROWS) * sizeof(float) + 255) & ~(size_t)255;
    char*  xq      = base + off_xq;
    size_t off_cq  = off_xq + (size_t)XROWS * DIM;
    char*  cq      = base + off_cq;
    size_t need    = off_cq + (size_t)CROWS * DIM;
    size_t off_cbr = (need + 255) & ~(size_t)255;
    short* cbr     = (short*)(base + off_cbr);
    size_t need2   = off_cbr + (size_t)CROWS * DIM * sizeof(short);

    hipMemsetAsync(cnt, 0, XROWS * sizeof(int), stream);

    if (ws_size >= need) {
        short* cbr_arg = (ws_size >= need2) ? cbr : nullptr;
        convert_i8_kernel<<<(XROWS + CROWS) / 4, 256, 0, stream>>>(x, cb, inv_all, qsc, xq, cq, cbr_arg);
        filter11_kernel<<<(XROWS / 128) * (CROWS / 128), 512, 0, stream>>>(xq, cq, qsc, cnt, cand);
        refine_kernel<<<XROWS, 256, 0, stream>>>(x, cb, cbr_arg, inv_all, cnt, cand, out);
    } else {
        norm_kernel<<<(XROWS + CROWS) / 4, 256, 0, stream>>>(x, cb, inv_all);
        filter_fb_kernel<<<64 * NSEG, 256, 0, stream>>>(x, cb, inv_all, cnt, cand);
        refine_kernel<<<XROWS, 256, 0, stream>>>(x, cb, (const short*)nullptr, inv_all, cnt, cand, out);
    }
}

// Round 17
// 538.754 us; speedup vs baseline: 2.5693x; 1.0034x over previous
//
#include <hip/hip_runtime.h>
#include <hip/hip_bf16.h>

#define XROWS 8192
#define CROWS 32768
#define DIM   768
#define KSEL  32
#define CAND_CAP 256
#define TAU 0.095f
#define WIN_W 0.003f   // rescore half-width: ~6.5 sigma of i8 sim err (sigma ~ 4.6e-4)

typedef __attribute__((ext_vector_type(8))) short bf16x8;
typedef __attribute__((ext_vector_type(4))) short s16x4;
typedef __attribute__((ext_vector_type(4))) float f32x4;
typedef __attribute__((ext_vector_type(4))) int   i32x4;
typedef __attribute__((ext_vector_type(4))) unsigned short u16x4;

__device__ inline short f2bf(float f) {
    unsigned int b = __builtin_bit_cast(unsigned int, f);
    b += 0x7fffu + ((b >> 16) & 1u);
    return (short)(b >> 16);
}
__device__ inline float bf2f(unsigned short u) {
    unsigned int b = ((unsigned int)u) << 16;
    return __builtin_bit_cast(float, b);
}

__device__ inline void gload_lds16(const void* g, void* l) {
    __builtin_amdgcn_global_load_lds((const __attribute__((address_space(1))) void*)g,
                                     (__attribute__((address_space(3))) void*)l,
                                     16, 0, 0);
}

// ============ pre-pass: norms + i8-quantized normalized copies + raw bf16 cb ====
__global__ __launch_bounds__(256) void convert_i8_kernel(const float* __restrict__ x,
                                                         const float* __restrict__ cb,
                                                         float* __restrict__ inv_all,
                                                         float* __restrict__ qsc,
                                                         char* __restrict__ xq,
                                                         char* __restrict__ cq,
                                                         short* __restrict__ cbr) {
    int wid  = (blockIdx.x * blockDim.x + threadIdx.x) >> 6;  // one wave per row
    int lane = threadIdx.x & 63;
    if (wid >= XROWS + CROWS) return;
    const float* src = (wid < XROWS) ? (x + (size_t)wid * DIM)
                                     : (cb + (size_t)(wid - XROWS) * DIM);
    char* dst = (wid < XROWS) ? (xq + (size_t)wid * DIM)
                              : (cq + (size_t)(wid - XROWS) * DIM);
    f32x4 v[3];
    float ss = 0.f, am = 0.f;
#pragma unroll
    for (int j = 0; j < 3; ++j) {
        v[j] = *(const f32x4*)&src[(lane + 64 * j) * 4];
        ss += v[j][0]*v[j][0] + v[j][1]*v[j][1] + v[j][2]*v[j][2] + v[j][3]*v[j][3];
        am = fmaxf(am, fmaxf(fmaxf(fabsf(v[j][0]), fabsf(v[j][1])),
                             fmaxf(fabsf(v[j][2]), fabsf(v[j][3]))));
    }
#pragma unroll
    for (int s = 32; s >= 1; s >>= 1) {
        ss += __shfl_xor(ss, s, 64);
        am = fmaxf(am, __shfl_xor(am, s, 64));
    }
    float inv  = 1.0f / fmaxf(sqrtf(ss), 1e-8f);
    float amn  = fmaxf(am * inv, 1e-8f);     // absmax of normalized row
    float qs   = amn * (1.0f / 127.0f);
    float iq   = 127.0f / amn;
    if (lane == 0) { inv_all[wid] = inv; qsc[wid] = qs; }
#pragma unroll
    for (int j = 0; j < 3; ++j) {
        int b0 = __float2int_rn(fminf(fmaxf(v[j][0] * inv * iq, -127.f), 127.f)) & 0xff;
        int b1 = __float2int_rn(fminf(fmaxf(v[j][1] * inv * iq, -127.f), 127.f)) & 0xff;
        int b2 = __float2int_rn(fminf(fmaxf(v[j][2] * inv * iq, -127.f), 127.f)) & 0xff;
        int b3 = __float2int_rn(fminf(fmaxf(v[j][3] * inv * iq, -127.f), 127.f)) & 0xff;
        *(int*)&dst[(size_t)(lane + 64 * j) * 4] = b0 | (b1 << 8) | (b2 << 16) | (b3 << 24);
    }
    if (cbr != nullptr && wid >= XROWS) {   // RAW bf16 copy (NOT normalized!)
        short* d2 = cbr + (size_t)(wid - XROWS) * DIM;
#pragma unroll
        for (int j = 0; j < 3; ++j) {
            s16x4 o;
            o[0] = f2bf(v[j][0]); o[1] = f2bf(v[j][1]);
            o[2] = f2bf(v[j][2]); o[3] = f2bf(v[j][3]);
            *(s16x4*)&d2[(lane + 64 * j) * 4] = o;
        }
    }
}

// ============ filter11 (R13-proven, 377us): i8 128x128 dbuf, 8w x (32x64) =======
// 32KB LDS / 4 blocks/CU, 512 threads -> 32 waves/CU (HW occupancy cap).
#define NT8 12   // 768/64

__device__ __forceinline__ i32x4 rdfrag_i8(const char* base, int row, int logslot) {
    int byte = (row << 6) + ((logslot ^ ((row >> 1) & 3)) << 4);
    return *(const i32x4*)(base + byte);
}

__global__ __launch_bounds__(512, 8) void filter11_kernel(const char* __restrict__ xq,
                                                          const char* __restrict__ cq,
                                                          const float* __restrict__ qsc,
                                                          int* __restrict__ cnt,
                                                          int2* __restrict__ cand) {
    __shared__ char As[2][128 * 64];   // 2 x 8 KB
    __shared__ char Bs[2][128 * 64];   // 2 x 8 KB  (32 KB total)

    const int bid  = blockIdx.x;
    const int rt   = ((bid & 7) << 3) | ((bid >> 3) & 7);
    const int ct   = bid >> 6;
    const int row0 = rt * 128;
    const int col0 = ct * 128;

    const int t      = threadIdx.x;   // 0..511
    const int lane   = t & 63;
    const int w      = t >> 6;        // 0..7
    const int wr     = w >> 1;        // 0..3: rows wr*32..+31
    const int wc     = w & 1;         // 0..1: cols wc*64..+63
    const int lane15 = lane & 15;
    const int slot   = lane >> 4;     // logical 16B k-slot, 0..3

    // staging: thread t covers tile byte f = t*16 (one A + one B load per tile)
    const int f_   = t * 16;
    const int sr_  = f_ >> 6;                               // row 0..127
    const int p_   = (f_ >> 4) & 3;                         // physical 16B chunk
    const int sce_ = (p_ ^ ((sr_ >> 1) & 3)) << 4;          // pre-swizzled src byte

#define STG(BUF_, KT_) do {                                                            \
    gload_lds16(&xq[(size_t)(row0 + sr_) * DIM + (KT_) * 64 + sce_],                   \
                (char*)&As[BUF_][0] + w * 1024);                                       \
    gload_lds16(&cq[(size_t)(col0 + sr_) * DIM + (KT_) * 64 + sce_],                   \
                (char*)&Bs[BUF_][0] + w * 1024);                                       \
} while (0)

    i32x4 acc[2][4];
    const i32x4 izero = {0, 0, 0, 0};
#pragma unroll
    for (int m = 0; m < 2; ++m)
#pragma unroll
        for (int n = 0; n < 4; ++n) acc[m][n] = izero;

    STG(0, 0);
    asm volatile("s_waitcnt vmcnt(0)" ::: "memory");
    __builtin_amdgcn_s_barrier();
    __builtin_amdgcn_sched_barrier(0);

#pragma unroll 1
    for (int kt = 0; kt < NT8; ++kt) {
        const int buf = kt & 1;
        if (kt + 1 < NT8) STG(buf ^ 1, kt + 1);   // other buf: sealed last barrier
        i32x4 a_[2], b_[4];
#pragma unroll
        for (int m = 0; m < 2; ++m)
            a_[m] = rdfrag_i8(&As[buf][0], wr * 32 + m * 16 + lane15, slot);
#pragma unroll
        for (int n = 0; n < 4; ++n)
            b_[n] = rdfrag_i8(&Bs[buf][0], wc * 64 + n * 16 + lane15, slot);
        asm volatile("s_waitcnt lgkmcnt(0)" ::: "memory");
        __builtin_amdgcn_sched_barrier(0);
        __builtin_amdgcn_s_setprio(1);
#pragma unroll
        for (int m = 0; m < 2; ++m)
#pragma unroll
            for (int n = 0; n < 4; ++n)
                acc[m][n] = __builtin_amdgcn_mfma_i32_16x16x64_i8(a_[m], b_[n], acc[m][n], 0, 0, 0);
        __builtin_amdgcn_s_setprio(0);
        asm volatile("s_waitcnt vmcnt(0)" ::: "memory");  // own 2 next-tile stages in
        __builtin_amdgcn_s_barrier();                     // all waves' stages landed
        __builtin_amdgcn_sched_barrier(0);
    }
#undef STG

    // epilogue: dequant (qsc[row]*qsc[XROWS+col]) + threshold push
    const int rbase = row0 + wr * 32 + slot * 4;
    const int cbase = col0 + wc * 64 + lane15;
    float qc4[4];
#pragma unroll
    for (int n = 0; n < 4; ++n) qc4[n] = qsc[XROWS + cbase + n * 16];
#pragma unroll
    for (int m = 0; m < 2; ++m)
#pragma unroll
        for (int q = 0; q < 4; ++q) {
            const int row = rbase + m * 16 + q;
            const float qx = qsc[row];
#pragma unroll
            for (int n = 0; n < 4; ++n) {
                float s = (float)acc[m][n][q] * qx * qc4[n];
                if (s >= TAU) {
                    int col = cbase + n * 16;
                    int pos = atomicAdd(&cnt[row], 1);
                    if (pos < CAND_CAP)
                        cand[(size_t)row * CAND_CAP + pos] = make_int2(__float_as_int(s), col);
                }
            }
        }
}

// ============ fallback filter (fp32 inputs, small-ws path) ======================
#define BM 128
#define BN 128
#define FBK 32
#define NSEG 16
#define SEGCOLS (CROWS / NSEG)
__global__ __launch_bounds__(256) void filter_fb_kernel(const float* __restrict__ x,
                                                        const float* __restrict__ cb,
                                                        const float* __restrict__ inv_all,
                                                        int* __restrict__ cnt,
                                                        int2* __restrict__ cand) {
    __shared__ short As[BM][FBK + 8];
    __shared__ short Bs[BN][FBK + 8];
    const int rt   = blockIdx.x >> 4;
    const int seg  = blockIdx.x & 15;
    const int row0 = rt * BM;
    const int segc0 = seg * SEGCOLS;
    const int t    = threadIdx.x;
    const int lane = t & 63;
    const int w    = t >> 6;
    const int wr   = w >> 1, wc = w & 1;

    for (int ch = 0; ch < SEGCOLS / BN; ++ch) {
        const int col0 = segc0 + ch * BN;
        f32x4 acc[4][4];
        const f32x4 zero = {0.f, 0.f, 0.f, 0.f};
#pragma unroll
        for (int m = 0; m < 4; ++m)
#pragma unroll
            for (int n = 0; n < 4; ++n) acc[m][n] = zero;

        for (int kk = 0; kk < DIM; kk += FBK) {
            __syncthreads();
#pragma unroll
            for (int p = 0; p < 4; ++p) {
                int f4 = t + 256 * p;
                int r  = f4 >> 3;
                int c  = (f4 & 7) * 4;
                f32x4 v  = *(const f32x4*)&x[(size_t)(row0 + r) * DIM + kk + c];
                float iv = inv_all[row0 + r];
                s16x4 o;
                o[0] = f2bf(v[0] * iv); o[1] = f2bf(v[1] * iv);
                o[2] = f2bf(v[2] * iv); o[3] = f2bf(v[3] * iv);
                *(s16x4*)&As[r][c] = o;
            }
#pragma unroll
            for (int p = 0; p < 4; ++p) {
                int f4 = t + 256 * p;
                int r  = f4 >> 3;
                int c  = (f4 & 7) * 4;
                f32x4 v  = *(const f32x4*)&cb[(size_t)(col0 + r) * DIM + kk + c];
                float iv = inv_all[XROWS + col0 + r];
                s16x4 o;
                o[0] = f2bf(v[0] * iv); o[1] = f2bf(v[1] * iv);
                o[2] = f2bf(v[2] * iv); o[3] = f2bf(v[3] * iv);
                *(s16x4*)&Bs[r][c] = o;
            }
            __syncthreads();

            bf16x8 af[4], bfr[4];
#pragma unroll
            for (int m = 0; m < 4; ++m)
                af[m] = *(const bf16x8*)&As[wr * 64 + m * 16 + (lane & 15)][(lane >> 4) * 8];
#pragma unroll
            for (int n = 0; n < 4; ++n)
                bfr[n] = *(const bf16x8*)&Bs[wc * 64 + n * 16 + (lane & 15)][(lane >> 4) * 8];
#pragma unroll
            for (int m = 0; m < 4; ++m)
#pragma unroll
                for (int n = 0; n < 4; ++n)
                    acc[m][n] = __builtin_amdgcn_mfma_f32_16x16x32_bf16(af[m], bfr[n], acc[m][n], 0, 0, 0);
        }

        const int rbase = row0 + wr * 64 + (lane >> 4) * 4;
        const int cbase = col0 + wc * 64 + (lane & 15);
#pragma unroll
        for (int m = 0; m < 4; ++m)
#pragma unroll
            for (int n = 0; n < 4; ++n)
#pragma unroll
                for (int q = 0; q < 4; ++q) {
                    float s = acc[m][n][q];
                    if (s >= TAU) {
                        int row = rbase + m * 16 + q;
                        int col = cbase + n * 16;
                        int pos = atomicAdd(&cnt[row], 1);
                        if (pos < CAND_CAP)
                            cand[(size_t)row * CAND_CAP + pos] = make_int2(__float_as_int(s), col);
                    }
                }
    }
}

__global__ __launch_bounds__(256) void norm_kernel(const float* __restrict__ x,
                                                   const float* __restrict__ cb,
                                                   float* __restrict__ inv_all) {
    int wid  = (blockIdx.x * blockDim.x + threadIdx.x) >> 6;
    int lane = threadIdx.x & 63;
    if (wid >= XROWS + CROWS) return;
    const float* src = (wid < XROWS) ? (x + (size_t)wid * DIM)
                                     : (cb + (size_t)(wid - XROWS) * DIM);
    float ss = 0.f;
#pragma unroll
    for (int j = 0; j < 3; ++j) {
        f32x4 v = *(const f32x4*)&src[(lane + 64 * j) * 4];
        ss += v[0]*v[0] + v[1]*v[1] + v[2]*v[2] + v[3]*v[3];
    }
#pragma unroll
    for (int s = 32; s >= 1; s >>= 1) ss += __shfl_xor(ss, s, 64);
    if (lane == 0) inv_all[wid] = 1.0f / fmaxf(sqrtf(ss), 1e-8f);
}

// ============ refine V5: TWO rows per block, shared-barrier bitonic sorts =======
// Sorts are barrier-bound (R16: rescore/gather polish was null). Two independent
// 256-sorts share every __syncthreads (each thread does both rows' exchange);
// the two 128-window sorts run in parallel (t<128 row0, t>=128 row1).
__global__ __launch_bounds__(256) void refine2_kernel(const float* __restrict__ x,
                                                      const float* __restrict__ cb,
                                                      const short* __restrict__ cbr,
                                                      const float* __restrict__ inv_all,
                                                      const int* __restrict__ cnt,
                                                      const int2* __restrict__ cand,
                                                      float* __restrict__ out) {
    __shared__ float xs[2 * DIM];
    __shared__ float sv[2][CAND_CAP];
    __shared__ int   si[2][CAND_CAP];
    __shared__ float wsv[2][128];
    __shared__ int   wsi[2][128];
    __shared__ int   cdef[2][4], cwin[2][4];

    const int r0 = blockIdx.x * 2;
    const int t  = threadIdx.x;
#pragma unroll
    for (int j = 0; j < 3; ++j) {
        xs[t + 256 * j]       = x[(size_t)r0 * DIM + t + 256 * j];
        xs[DIM + t + 256 * j] = x[(size_t)(r0 + 1) * DIM + t + 256 * j];
    }

#pragma unroll
    for (int r = 0; r < 2; ++r) {
        int nc = cnt[r0 + r];
        if (nc > CAND_CAP) nc = CAND_CAP;
        int2 c = (t < nc) ? cand[(size_t)(r0 + r) * CAND_CAP + t]
                          : make_int2((int)0xFF800000u /* -inf */, 0x7fffffff);
        sv[r][t] = __int_as_float(c.x);
        si[r][t] = c.y;
    }
    if (t < 128) {
        wsv[0][t] = -INFINITY; wsi[0][t] = 0x7fffffff;
        wsv[1][t] = -INFINITY; wsi[1][t] = 0x7fffffff;
    }
    __syncthreads();

    // two bitonic-256 sorts, shared barriers: desc sim, ties -> asc idx
    for (int k2 = 2; k2 <= 256; k2 <<= 1) {
        for (int j = k2 >> 1; j > 0; j >>= 1) {
            int p = t ^ j;
            if (p > t) {
#pragma unroll
                for (int r = 0; r < 2; ++r) {
                    float s1 = sv[r][t], s2 = sv[r][p];
                    int   i1 = si[r][t], i2 = si[r][p];
                    bool lt_tp = (s1 < s2) || (s1 == s2 && i1 > i2);
                    bool lt_pt = (s2 < s1) || (s1 == s2 && i2 > i1);
                    bool doswap = ((t & k2) == 0) ? lt_tp : lt_pt;
                    if (doswap) { sv[r][t] = s2; sv[r][p] = s1; si[r][t] = i2; si[r][p] = i1; }
                }
            }
            __syncthreads();
        }
    }

    // classify both rows: definite (sv > B+W) / window [B-W, B+W]
#pragma unroll
    for (int r = 0; r < 2; ++r) {
        const float B = sv[r][31];
        bool defin = (sv[r][t] > B + WIN_W);
        bool win   = (sv[r][t] >= B - WIN_W) && !defin;
        unsigned long long bd = __ballot(defin);
        unsigned long long bw = __ballot(win);
        if ((t & 63) == 0) { cdef[r][t >> 6] = __popcll(bd); cwin[r][t >> 6] = __popcll(bw); }
    }
    __syncthreads();
    int d_[2], m_[2];
#pragma unroll
    for (int r = 0; r < 2; ++r) {
        d_[r] = cdef[r][0] + cdef[r][1] + cdef[r][2] + cdef[r][3];   // <= 32
        int mm = cwin[r][0] + cwin[r][1] + cwin[r][2] + cwin[r][3];
        m_[r] = (mm > 128) ? 128 : mm;
    }

    // exact fp32 rescore, 8 lanes per candidate (octets), both rows
    const int oct = t >> 3, sub8 = t & 7;
#pragma unroll
    for (int p2 = 0; p2 < 4; ++p2) {
#pragma unroll
        for (int r = 0; r < 2; ++r) {
            int ci = p2 * 32 + oct;
            if (ci < m_[r]) {
                int col = si[r][d_[r] + ci];
                if (col >= 0 && col < CROWS) {
                    const float* cp = cb + (size_t)col * DIM;
                    const float* xp = xs + r * DIM;
                    float a0 = 0.f, a1 = 0.f, a2 = 0.f, a3 = 0.f;
#pragma unroll 4
                    for (int i = 0; i < 24; ++i) {
                        f32x4 c4 = *(const f32x4*)&cp[sub8 * 4 + i * 32];
                        f32x4 x4 = *(const f32x4*)&xp[sub8 * 4 + i * 32];
                        a0 = fmaf(x4[0], c4[0], a0);
                        a1 = fmaf(x4[1], c4[1], a1);
                        a2 = fmaf(x4[2], c4[2], a2);
                        a3 = fmaf(x4[3], c4[3], a3);
                    }
                    float dd = (a0 + a1) + (a2 + a3);
                    dd += __shfl_xor(dd, 1, 64);
                    dd += __shfl_xor(dd, 2, 64);
                    dd += __shfl_xor(dd, 4, 64);
                    if (sub8 == 0) {
                        wsv[r][ci] = dd * inv_all[r0 + r] * inv_all[XROWS + col];
                        wsi[r][ci] = col;
                    }
                }
            }
        }
    }
    __syncthreads();

    // two bitonic-128 window sorts in parallel: t<128 -> row0, t>=128 -> row1
    {
        const int rr = t >> 7;          // 0 or 1
        const int u  = t & 127;
        for (int k2 = 2; k2 <= 128; k2 <<= 1) {
            for (int j = k2 >> 1; j > 0; j >>= 1) {
                int p = u ^ j;
                if (p > u) {
                    float s1 = wsv[rr][u], s2 = wsv[rr][p];
                    int   i1 = wsi[rr][u], i2 = wsi[rr][p];
                    bool lt_tp = (s1 < s2) || (s1 == s2 && i1 > i2);
                    bool lt_pt = (s2 < s1) || (s1 == s2 && i2 > i1);
                    bool doswap = ((u & k2) == 0) ? lt_tp : lt_pt;
                    if (doswap) { wsv[rr][u] = s2; wsv[rr][p] = s1; wsi[rr][u] = i2; wsi[rr][p] = i1; }
                }
                __syncthreads();
            }
        }
    }

    // final sets: d definite + best (32-d) of window; vectorized gather-sum.
    if (t < 192) {
#pragma unroll
        for (int r = 0; r < 2; ++r) {
            float o0 = 0.f, o1 = 0.f, o2 = 0.f, o3 = 0.f;
            if (cbr != nullptr) {
                for (int j = 0; j < KSEL; ++j) {
                    int cc = (j < d_[r]) ? si[r][j] : wsi[r][j - d_[r]];
                    if (cc >= 0 && cc < CROWS) {
                        u16x4 r4 = *(const u16x4*)((const unsigned short*)(cbr + (size_t)cc * DIM) + t * 4);
                        o0 += bf2f(r4[0]);
                        o1 += bf2f(r4[1]);
                        o2 += bf2f(r4[2]);
                        o3 += bf2f(r4[3]);
                    }
                }
            } else {
                for (int j = 0; j < KSEL; ++j) {
                    int cc = (j < d_[r]) ? si[r][j] : wsi[r][j - d_[r]];
                    if (cc >= 0 && cc < CROWS) {
                        f32x4 r4 = *(const f32x4*)&cb[(size_t)cc * DIM + t * 4];
                        o0 += r4[0];
                        o1 += r4[1];
                        o2 += r4[2];
                        o3 += r4[3];
                    }
                }
            }
            f32x4 ov = {o0, o1, o2, o3};
            *(f32x4*)&out[(size_t)(r0 + r) * DIM + t * 4] = ov;
        }
    }
}

extern "C" void kernel_launch(void* const* d_in, const int* in_sizes, int n_in,
                              void* d_out, int out_size, void* d_ws, size_t ws_size,
                              hipStream_t stream) {
    const float* x  = (const float*)d_in[0];
    const float* cb = (const float*)d_in[1];
    float* out = (float*)d_out;

    // ws layout: cnt | cand(int2) | inv_all | qsc | xq i8 | cq i8 [| cbr bf16]
    char* base = (char*)d_ws;
    int*   cnt     = (int*)base;
    int2*  cand    = (int2*)(base + (size_t)XROWS * sizeof(int));
    size_t off_inv = (size_t)XROWS * sizeof(int) + (size_t)XROWS * CAND_CAP * sizeof(int2);
    float* inv_all = (float*)(base + off_inv);
    size_t off_qsc = off_inv + (size_t)(XROWS + CROWS) * sizeof(float);
    float* qsc     = (float*)(base + off_qsc);
    size_t off_xq  = (off_qsc + (size_t)(XROWS + CROWS) * sizeof(float) + 255) & ~(size_t)255;
    char*  xq      = base + off_xq;
    size_t off_cq  = off_xq + (size_t)XROWS * DIM;
    char*  cq      = base + off_cq;
    size_t need    = off_cq + (size_t)CROWS * DIM;
    size_t off_cbr = (need + 255) & ~(size_t)255;
    short* cbr     = (short*)(base + off_cbr);
    size_t need2   = off_cbr + (size_t)CROWS * DIM * sizeof(short);

    hipMemsetAsync(cnt, 0, XROWS * sizeof(int), stream);

    if (ws_size >= need) {
        short* cbr_arg = (ws_size >= need2) ? cbr : nullptr;
        convert_i8_kernel<<<(XROWS + CROWS) / 4, 256, 0, stream>>>(x, cb, inv_all, qsc, xq, cq, cbr_arg);
        filter11_kernel<<<(XROWS / 128) * (CROWS / 128), 512, 0, stream>>>(xq, cq, qsc, cnt, cand);
        refine2_kernel<<<XROWS / 2, 256, 0, stream>>>(x, cb, cbr_arg, inv_all, cnt, cand, out);
    } else {
        norm_kernel<<<(XROWS + CROWS) / 4, 256, 0, stream>>>(x, cb, inv_all);
        filter_fb_kernel<<<64 * NSEG, 256, 0, stream>>>(x, cb, inv_all, cnt, cand);
        refine2_kernel<<<XROWS / 2, 256, 0, stream>>>(x, cb, (const short*)nullptr, inv_all, cnt, cand, out);
    }
}